// Round 9
// baseline (174.353 us; speedup 1.0000x reference)
//
#include <hip/hip_runtime.h>
#include <stdint.h>

using i32x4  = __attribute__((ext_vector_type(4))) int;
using i32x8  = __attribute__((ext_vector_type(8))) int;
using f32x16 = __attribute__((ext_vector_type(16))) float;
using f32x4v = __attribute__((ext_vector_type(4))) float;   // for nontemporal

#define M_ROWS 8192
#define N_COLS 4096
#define K_DIM  4096
#define KB_ROW 2048          // bytes per packed fp4 row (2 elems/byte)
#define BM 256
#define BN 256
#define SC1 0x7F7F7F7F       // E8M0 = 127 -> scale 1.0, all bytes

// ------------- Pass 1: binarize f32 -> fp4 e2m1 {+1,-1} nibbles -------------
#define XDW   ((size_t)M_ROWS * K_DIM / 8)                  // 4,194,304
#define TOTDW (((size_t)(M_ROWS + N_COLS)) * K_DIM / 8)     // 6,291,456

__device__ __forceinline__ unsigned pack8(f32x4v a, f32x4v b) {
  unsigned neg =
      ((a[0] > 0.f ? 0u : 1u) << 3)  | ((a[1] > 0.f ? 0u : 1u) << 7)  |
      ((a[2] > 0.f ? 0u : 1u) << 11) | ((a[3] > 0.f ? 0u : 1u) << 15) |
      ((b[0] > 0.f ? 0u : 1u) << 19) | ((b[1] > 0.f ? 0u : 1u) << 23) |
      ((b[2] > 0.f ? 0u : 1u) << 27) | ((b[3] > 0.f ? 0u : 1u) << 31);
  return 0x22222222u | neg;
}

__global__ __launch_bounds__(256) void binarize_fp4_fused(
    const f32x4v* __restrict__ x, const f32x4v* __restrict__ w,
    uint4* __restrict__ out) {
  size_t u = (size_t)blockIdx.x * blockDim.x + threadIdx.x;  // quad index
  size_t stride = (size_t)gridDim.x * blockDim.x;
  for (; u < TOTDW / 4; u += stride) {
    size_t d = u * 4;
    const f32x4v* s;
    size_t j;
    if (d < XDW) { s = x; j = d * 2; }      // XDW % 4 == 0: no straddle
    else         { s = w; j = (d - XDW) * 2; }
    f32x4v f0 = __builtin_nontemporal_load(&s[j]);
    f32x4v f1 = __builtin_nontemporal_load(&s[j + 1]);
    f32x4v f2 = __builtin_nontemporal_load(&s[j + 2]);
    f32x4v f3 = __builtin_nontemporal_load(&s[j + 3]);
    f32x4v f4 = __builtin_nontemporal_load(&s[j + 4]);
    f32x4v f5 = __builtin_nontemporal_load(&s[j + 5]);
    f32x4v f6 = __builtin_nontemporal_load(&s[j + 6]);
    f32x4v f7 = __builtin_nontemporal_load(&s[j + 7]);
    uint4 o;
    o.x = pack8(f0, f1);
    o.y = pack8(f2, f3);
    o.z = pack8(f4, f5);
    o.w = pack8(f6, f7);
    out[u] = o;
  }
}

// ---------------- global -> LDS direct (16B per lane) ----------------
#define GLOAD(gsrc, ldst)                                                    \
  __builtin_amdgcn_global_load_lds(                                          \
      (const __attribute__((address_space(1))) void*)(gsrc),                 \
      (__attribute__((address_space(3))) void*)(ldst), 16, 0, 0)

// ------ Pass 2: fp4 MFMA GEMM, 256^2, 16 waves, K-major LDS -------------
// LDS per operand: [2 buf][2 khalf][16 KB unit]. Within a unit
// (256 rows x 64 B khalf):  addr = u*2048 + (2*ks+lh)*512 + (row&31)*16,
// u = row>>5. A fragment read (rows base..base+31, 16B k-chunk lh) is then
// EXACTLY base + lane*16 -> linear, conflict-free by construction (same
// pattern as the gload_lds write). All ds_reads = 1 VGPR base + immediate.
// Staging: thread t covers unit chunks (t&511) and (t&511)+512 -> global
// row ((c>>7)*32 + (c&31)), byte col ((c>>5)&3)*16; waves 0-7 stage A,
// waves 8-15 stage B. 2 gloads/thread/phase; vmcnt(2) induction (never 0
// in the main loop), vmcnt(0) only in the peeled last tile.

#define VM2BAR                                                               \
  asm volatile("s_waitcnt vmcnt(2)" ::: "memory");                           \
  __builtin_amdgcn_s_barrier();

#define VM0BAR                                                               \
  asm volatile("s_waitcnt vmcnt(0)" ::: "memory");                           \
  __builtin_amdgcn_s_barrier();

#define STG(KH, NB, KBo)                                                     \
  GLOAD(sBase + (KBo) + (KH) * 64, lBase + (NB) + (KH) * 16384);             \
  GLOAD(sBase + (KBo) + (KH) * 64 + 262144,                                  \
        lBase + (NB) + (KH) * 16384 + 8192)

#define DO_PHASE(BUF, KH, STAGE_STMT, CLOSE_STMT)                            \
  {                                                                          \
    STAGE_STMT                                                               \
    __builtin_amdgcn_s_setprio(1);                                           \
    _Pragma("unroll")                                                        \
    for (int ks = 0; ks < 2; ++ks) {                                         \
      *(i32x4*)&bf8[0] =                                                     \
          *(const i32x4*)(bRd + (BUF) + (KH) + ks * 1024);                   \
      *(i32x4*)&bf8[1] =                                                     \
          *(const i32x4*)(bRd + (BUF) + (KH) + 2048 + ks * 1024);            \
      *(i32x4*)&af8[0] =                                                     \
          *(const i32x4*)(aRd + (BUF) + (KH) + ks * 1024);                   \
      *(i32x4*)&af8[1] =                                                     \
          *(const i32x4*)(aRd + (BUF) + (KH) + 2048 + ks * 1024);            \
      acc[0][0] = __builtin_amdgcn_mfma_scale_f32_32x32x64_f8f6f4(           \
          af8[0], bf8[0], acc[0][0], 4, 4, 0, SC1, 0, SC1);                  \
      acc[0][1] = __builtin_amdgcn_mfma_scale_f32_32x32x64_f8f6f4(           \
          af8[0], bf8[1], acc[0][1], 4, 4, 0, SC1, 0, SC1);                  \
      acc[1][0] = __builtin_amdgcn_mfma_scale_f32_32x32x64_f8f6f4(           \
          af8[1], bf8[0], acc[1][0], 4, 4, 0, SC1, 0, SC1);                  \
      acc[1][1] = __builtin_amdgcn_mfma_scale_f32_32x32x64_f8f6f4(           \
          af8[1], bf8[1], acc[1][1], 4, 4, 0, SC1, 0, SC1);                  \
    }                                                                        \
    __builtin_amdgcn_s_setprio(0);                                           \
    CLOSE_STMT                                                               \
  }

#define TILE(BUF, NB, KBo)                                                   \
  DO_PHASE(BUF, 0,     STG(0, NB, KBo);, VM2BAR)                             \
  DO_PHASE(BUF, 16384, STG(1, NB, KBo);, VM2BAR)

#define TILE_LAST(BUF)                                                       \
  DO_PHASE(BUF, 0, , VM0BAR)                                                 \
  DO_PHASE(BUF, 16384, , )

__global__ __launch_bounds__(1024, 4) void bgemm_fp4_16w(
    const unsigned char* __restrict__ xa, const unsigned char* __restrict__ wb,
    const float* __restrict__ bias, float* __restrict__ y) {
  __shared__ __align__(16) unsigned char As[65536];
  __shared__ __align__(16) unsigned char Bs[65536];

  const int tid  = threadIdx.x;
  const int lane = tid & 63;
  const int w16  = tid >> 6;   // wave 0..15
  const int wr   = w16 >> 2;   // wave M-row 0..3 (64 rows each)
  const int wc   = w16 & 3;    // wave N-col 0..3 (64 cols each)

  // bijective XCD swizzle (512 blocks, 512 % 8 == 0)
  const int id = blockIdx.x;
  const int sw = ((id & 7) << 6) | (id >> 3);
  const int m0 = (sw >> 4) * BM;
  const int n0 = (sw & 15) * BN;

  // ---- staging geometry: chunk c -> row (c>>7)*32 + (c&31), col ((c>>5)&3)*16
  const int c   = tid & 511;
  const int rl  = ((c >> 7) << 5) + (c & 31);   // 0..127
  const int col = ((c >> 5) & 3) << 4;          // 0,16,32,48
  const int isB = tid >> 9;
  const unsigned char* sBase =
      isB ? (wb + (size_t)(n0 + rl) * KB_ROW + col)
          : (xa + (size_t)(m0 + rl) * KB_ROW + col);
  unsigned char* lBase = (isB ? Bs : As) + ((w16 & 7) << 10);

  // ---- fragment-read bases (identity lane map)
  const unsigned char* aRd = As + wr * 4096 + lane * 16;
  const unsigned char* bRd = Bs + wc * 4096 + lane * 16;

  f32x16 acc[2][2];
#pragma unroll
  for (int i = 0; i < 2; ++i)
#pragma unroll
    for (int j = 0; j < 2; ++j)
#pragma unroll
      for (int e = 0; e < 16; ++e) acc[i][j][e] = 0.f;

  // fp4 data lives in the LOW 4 regs of the 8-reg operand; high half stays 0
  i32x8 af8[2], bf8[2];
#pragma unroll
  for (int i = 0; i < 2; ++i) {
    af8[i] = (i32x8){0, 0, 0, 0, 0, 0, 0, 0};
    bf8[i] = (i32x8){0, 0, 0, 0, 0, 0, 0, 0};
  }

  // prologue: stage tile 0 (kh0 then kh1); first batch must land
  STG(0, 0, 0);
  STG(1, 0, 0);
  asm volatile("s_waitcnt vmcnt(2)" ::: "memory");
  __builtin_amdgcn_s_barrier();

#pragma unroll 1
  for (int tp = 0; tp < 7; ++tp) {
    const int kb1 = tp * 256 + 128;   // tile 2tp+1
    const int kb2 = tp * 256 + 256;   // tile 2tp+2
    TILE(0, 32768, kb1)
    TILE(32768, 0, kb2)
  }
  TILE(0, 32768, 1920)   // tile 14, stages tile 15
  TILE_LAST(32768)       // tile 15

  // epilogue: 32x32 C/D map: col = lane&31, row = (reg&3)+8*(reg>>2)+4*(lane>>5)
  const int l31 = lane & 31;
  const int lh  = lane >> 5;
  float bv[2];
#pragma unroll
  for (int nf = 0; nf < 2; ++nf) bv[nf] = bias[n0 + wc * 64 + nf * 32 + l31];
#pragma unroll
  for (int mf = 0; mf < 2; ++mf) {
#pragma unroll
    for (int j = 0; j < 16; ++j) {
      const int fr = (j & 3) + 8 * (j >> 2) + 4 * lh;
      const int gr = m0 + wr * 64 + mf * 32 + fr;
      float* orow = y + (size_t)gr * N_COLS + n0 + wc * 64 + l31;
      orow[0]  = acc[mf][0][j] + bv[0];
      orow[32] = acc[mf][1][j] + bv[1];
    }
  }
}

// =========================================================================
extern "C" void kernel_launch(void* const* d_in, const int* in_sizes, int n_in,
                              void* d_out, int out_size, void* d_ws, size_t ws_size,
                              hipStream_t stream) {
  const float* x    = (const float*)d_in[0];
  const float* wgt  = (const float*)d_in[1];
  const float* bias = (const float*)d_in[2];
  float* y = (float*)d_out;

  unsigned char* xa = (unsigned char*)d_ws;             // 8192*2048 = 16 MB
  unsigned char* wb = xa + (size_t)M_ROWS * KB_ROW;     // 4096*2048 =  8 MB

  binarize_fp4_fused<<<3072, 256, 0, stream>>>(
      (const f32x4v*)x, (const f32x4v*)wgt, (uint4*)xa);

  bgemm_fp4_16w<<<512, 1024, 0, stream>>>(xa, wb, bias, y);
}

// Round 10
// 128.200 us; speedup vs baseline: 1.3600x; 1.3600x over previous
//
#include <hip/hip_runtime.h>
#include <stdint.h>

using i32x4  = __attribute__((ext_vector_type(4))) int;
using i32x8  = __attribute__((ext_vector_type(8))) int;
using f32x4  = __attribute__((ext_vector_type(4))) float;
using f32x4v = __attribute__((ext_vector_type(4))) float;

#define M_ROWS 8192
#define N_COLS 4096
#define K_DIM  4096
#define KB_ROW 2048          // bytes per packed fp4 row (2 elems/byte)
#define BM 256
#define BN 256
#define SC1 0x7F7F7F7F       // E8M0 = 127 -> scale 1.0, all bytes

// ------------- Pass 1: binarize f32 -> fp4 e2m1 {+1,-1} nibbles -------------
// element 8i+j of a row -> bits [4j+3:4j] of out dword i. +1=0x2, -1=0xA.
// 4 out-dwords (8 float4 loads, 128 B) per thread-iter; uint4 store.
#define XDW   ((size_t)M_ROWS * K_DIM / 8)                  // 4,194,304
#define TOTDW (((size_t)(M_ROWS + N_COLS)) * K_DIM / 8)     // 6,291,456

__device__ __forceinline__ unsigned pack8(f32x4v a, f32x4v b) {
  unsigned neg =
      ((a[0] > 0.f ? 0u : 1u) << 3)  | ((a[1] > 0.f ? 0u : 1u) << 7)  |
      ((a[2] > 0.f ? 0u : 1u) << 11) | ((a[3] > 0.f ? 0u : 1u) << 15) |
      ((b[0] > 0.f ? 0u : 1u) << 19) | ((b[1] > 0.f ? 0u : 1u) << 23) |
      ((b[2] > 0.f ? 0u : 1u) << 27) | ((b[3] > 0.f ? 0u : 1u) << 31);
  return 0x22222222u | neg;
}

__global__ __launch_bounds__(256) void binarize_fp4_fused(
    const f32x4v* __restrict__ x, const f32x4v* __restrict__ w,
    uint4* __restrict__ out) {
  size_t u = (size_t)blockIdx.x * blockDim.x + threadIdx.x;  // quad index
  size_t stride = (size_t)gridDim.x * blockDim.x;
  for (; u < TOTDW / 4; u += stride) {
    size_t d = u * 4;
    const f32x4v* s;
    size_t j;
    if (d < XDW) { s = x; j = d * 2; }      // XDW % 4 == 0: no straddle
    else         { s = w; j = (d - XDW) * 2; }
    f32x4v f0 = s[j], f1 = s[j + 1], f2 = s[j + 2], f3 = s[j + 3];
    f32x4v f4 = s[j + 4], f5 = s[j + 5], f6 = s[j + 6], f7 = s[j + 7];
    uint4 o;
    o.x = pack8(f0, f1);
    o.y = pack8(f2, f3);
    o.z = pack8(f4, f5);
    o.w = pack8(f6, f7);
    out[u] = o;
  }
}

// ---------------- global -> LDS direct (16B per lane) ----------------
#define GLOAD(gsrc, ldst)                                                    \
  __builtin_amdgcn_global_load_lds(                                          \
      (const __attribute__((address_space(1))) void*)(gsrc),                 \
      (__attribute__((address_space(3))) void*)(ldst), 16, 0, 0)

// -------- Pass 2: fp4 MFMA GEMM, 256^2 tile, 16x16x128, 4-phase ----------
// (best measured schedule: 82.5 us, round 4)
// LDS per operand: [2 buf][2 khalf][256 rows][64 B] = 64 KB; slot-XOR
// swizzle (slot ^ ((row>>1)&3)) applied on the global source (gload_lds
// writes linearly), undone on ds_read -> conflict-free b128 reads.
// Counted vmcnt(4) twice per tile, vmcnt(0) only in the peeled last tile.

#define STG_A(NB, KBo, KH)                                                   \
  GLOAD(aS0 + (KBo) + (KH) * 64, As + (NB) + (KH) * 16384 + dstW);           \
  GLOAD(aS1 + (KBo) + (KH) * 64, As + (NB) + (KH) * 16384 + 8192 + dstW)

#define STG_B(NB, KBo, KH)                                                   \
  GLOAD(bS0 + (KBo) + (KH) * 64, Bs + (NB) + (KH) * 16384 + dstW);           \
  GLOAD(bS1 + (KBo) + (KH) * 64, Bs + (NB) + (KH) * 16384 + 8192 + dstW)

#define DO_PHASE(BUFOFF, KHOFF, MH, BLOAD, STAGE_STMT, PRE_CLOSE)            \
  {                                                                          \
    STAGE_STMT                                                               \
    if (BLOAD) {                                                             \
      _Pragma("unroll")                                                      \
      for (int nf = 0; nf < 4; ++nf)                                         \
        *(i32x4*)&bf8[nf] =                                                  \
            *(const i32x4*)(Bs + (BUFOFF) + (KHOFF) + bRdOff + nf * 1024);   \
    }                                                                        \
    _Pragma("unroll")                                                        \
    for (int mf = 0; mf < 4; ++mf)                                           \
      *(i32x4*)&af8[mf] = *(const i32x4*)(As + (BUFOFF) + (KHOFF) +          \
                                          aRdOff + (MH) * 4096 + mf * 1024); \
    __builtin_amdgcn_s_barrier();                                            \
    __builtin_amdgcn_s_setprio(1);                                           \
    _Pragma("unroll")                                                        \
    for (int mf = 0; mf < 4; ++mf) {                                         \
      _Pragma("unroll")                                                      \
      for (int nf = 0; nf < 4; ++nf)                                         \
        acc[(MH) * 4 + mf][nf] =                                             \
            __builtin_amdgcn_mfma_scale_f32_16x16x128_f8f6f4(                \
                af8[mf], bf8[nf], acc[(MH) * 4 + mf][nf], 4, 4, 0, SC1, 0,   \
                SC1);                                                        \
    }                                                                        \
    __builtin_amdgcn_s_setprio(0);                                           \
    PRE_CLOSE                                                                \
    __builtin_amdgcn_s_barrier();                                            \
  }

#define TILE_NORMAL(BUFOFF, NBUFOFF, KBo)                                    \
  DO_PHASE(BUFOFF, 0, 0, true, STG_A(NBUFOFF, KBo, 0);, )                    \
  DO_PHASE(BUFOFF, 0, 1, false, STG_B(NBUFOFF, KBo, 0);,                     \
           asm volatile("s_waitcnt vmcnt(4)" ::: "memory");)                 \
  DO_PHASE(BUFOFF, 16384, 0, true, STG_A(NBUFOFF, KBo, 1);, )                \
  DO_PHASE(BUFOFF, 16384, 1, false, STG_B(NBUFOFF, KBo, 1);,                 \
           asm volatile("s_waitcnt vmcnt(4)" ::: "memory");)

#define TILE_LAST(BUFOFF)                                                    \
  DO_PHASE(BUFOFF, 0, 0, true, , )                                           \
  DO_PHASE(BUFOFF, 0, 1, false, ,                                            \
           asm volatile("s_waitcnt vmcnt(0)" ::: "memory");)                 \
  DO_PHASE(BUFOFF, 16384, 0, true, , )                                       \
  DO_PHASE(BUFOFF, 16384, 1, false, , )

__global__ __launch_bounds__(512, 2) void bgemm_fp4_8ph(
    const unsigned char* __restrict__ xa, const unsigned char* __restrict__ wb,
    const float* __restrict__ bias, float* __restrict__ y) {
  __shared__ __align__(16) unsigned char As[65536];
  __shared__ __align__(16) unsigned char Bs[65536];

  const int tid  = threadIdx.x;
  const int lane = tid & 63;
  const int w8   = tid >> 6;   // wave 0..7
  const int wr   = w8 >> 2;    // wave M-row 0..1 (128 rows each)
  const int wc   = w8 & 3;     // wave N-col 0..3 (64 cols each)

  // bijective XCD swizzle (512 blocks, 512 % 8 == 0)
  const int id = blockIdx.x;
  const int sw = ((id & 7) << 6) | (id >> 3);
  const int by = sw >> 4;      // 0..31 M-block
  const int bx = sw & 15;      // 0..15 N-block
  const int m0 = by * BM;
  const int n0 = bx * BN;

  // ---- staging geometry: thread covers LDS row tid>>2, slot tid&3
  const int r0  = tid >> 2;
  const int gsl = (((tid & 3) ^ ((tid >> 3) & 3)) << 4);  // inverse swizzle
  const unsigned char* aS0 = xa + (size_t)(m0 + r0) * KB_ROW + gsl;
  const unsigned char* aS1 = xa + (size_t)(m0 + 128 + r0) * KB_ROW + gsl;
  const unsigned char* bS0 = wb + (size_t)(n0 + r0) * KB_ROW + gsl;
  const unsigned char* bS1 = wb + (size_t)(n0 + 128 + r0) * KB_ROW + gsl;
  const int dstW = w8 * 1024;  // wave-uniform LDS dest (HW adds lane*16)

  // ---- fragment-read geometry (16x16x128 fp4: lane lr = row, kq = 16B grp)
  const int lr  = lane & 15;
  const int kq  = lane >> 4;
  const int rsw = (kq ^ ((lr >> 1) & 3)) << 4;   // swizzled read slot
  const int aRdOff = (wr * 128 + lr) * 64 + rsw; // + MH*4096 + mf*1024
  const int bRdOff = (wc * 64 + lr) * 64 + rsw;  // + nf*1024

  f32x4 acc[8][4];
#pragma unroll
  for (int i = 0; i < 8; ++i)
#pragma unroll
    for (int j = 0; j < 4; ++j) acc[i][j] = (f32x4){0.f, 0.f, 0.f, 0.f};

  // fp4 data lives in the LOW 4 regs of the 8-reg operand; high half stays 0
  i32x8 af8[4], bf8[4];
#pragma unroll
  for (int i = 0; i < 4; ++i) {
    af8[i] = (i32x8){0, 0, 0, 0, 0, 0, 0, 0};
    bf8[i] = (i32x8){0, 0, 0, 0, 0, 0, 0, 0};
  }

  // prologue: stage tile 0 (units A0,B0,A1,B1); wait first 2 units
  STG_A(0, 0, 0);
  STG_B(0, 0, 0);
  STG_A(0, 0, 1);
  STG_B(0, 0, 1);
  asm volatile("s_waitcnt vmcnt(4)" ::: "memory");
  __builtin_amdgcn_s_barrier();

#pragma unroll 1
  for (int tp = 0; tp < 7; ++tp) {
    const int kb1 = tp * 256 + 128;   // tile 2tp+1
    const int kb2 = tp * 256 + 256;   // tile 2tp+2
    TILE_NORMAL(0, 32768, kb1)
    TILE_NORMAL(32768, 0, kb2)
  }
  TILE_NORMAL(0, 32768, 1920)   // tile 14, stages tile 15
  TILE_LAST(32768)              // tile 15

  // epilogue: C/D map col = lane&15, row = kq*4 + j (shape-determined)
  float bv[4];
#pragma unroll
  for (int nf = 0; nf < 4; ++nf) bv[nf] = bias[n0 + wc * 64 + nf * 16 + lr];
#pragma unroll
  for (int fr = 0; fr < 8; ++fr) {
#pragma unroll
    for (int j = 0; j < 4; ++j) {
      const int gr = m0 + wr * 128 + fr * 16 + kq * 4 + j;
      float* orow = y + (size_t)gr * N_COLS + n0 + wc * 64 + lr;
#pragma unroll
      for (int nf = 0; nf < 4; ++nf)
        orow[nf * 16] = acc[fr][nf][j] + bv[nf];
    }
  }
}

// =========================================================================
extern "C" void kernel_launch(void* const* d_in, const int* in_sizes, int n_in,
                              void* d_out, int out_size, void* d_ws, size_t ws_size,
                              hipStream_t stream) {
  const float* x    = (const float*)d_in[0];
  const float* wgt  = (const float*)d_in[1];
  const float* bias = (const float*)d_in[2];
  float* y = (float*)d_out;

  unsigned char* xa = (unsigned char*)d_ws;             // 8192*2048 = 16 MB
  unsigned char* wb = xa + (size_t)M_ROWS * KB_ROW;     // 4096*2048 =  8 MB

  binarize_fp4_fused<<<3072, 256, 0, stream>>>(
      (const f32x4v*)x, (const f32x4v*)wgt, (uint4*)xa);

  bgemm_fp4_8ph<<<512, 512, 0, stream>>>(xa, wb, bias, y);
}